// Round 4
// baseline (568.351 us; speedup 1.0000x reference)
//
#include <hip/hip_runtime.h>
#include <math.h>

// Problem constants
#define SB 4
#define SS 2048
#define SD 1024
#define SH 16
#define SHD 64
#define SM (SB * SS) // 8192 rows

using f32x4 = __attribute__((ext_vector_type(4))) float;
using h8    = __attribute__((ext_vector_type(8))) _Float16;
using h4    = __attribute__((ext_vector_type(4))) _Float16;
using fp16x2 = __fp16 __attribute__((ext_vector_type(2)));
using fp16x4 = __fp16 __attribute__((ext_vector_type(4)));
using u32x4 = __attribute__((ext_vector_type(4))) unsigned int;

__device__ __forceinline__ unsigned short f2h(float x) {
  _Float16 h = (_Float16)x;
  return __builtin_bit_cast(unsigned short, h);
}

__device__ __forceinline__ void gld_lds16(const unsigned short* g, unsigned short* l) {
  __builtin_amdgcn_global_load_lds(
      (const __attribute__((address_space(1))) unsigned int*)g,
      (__attribute__((address_space(3))) unsigned int*)l, 16, 0, 0);
}

// ---------------- fused fp32 -> fp16 convert: X (blocks 0..8191) + 3 weights ----------
__global__ __launch_bounds__(256) void cvt_all(const float* __restrict__ hs,
    const float* __restrict__ w0, const float* __restrict__ w1, const float* __restrict__ w2,
    unsigned short* __restrict__ xo, unsigned short* __restrict__ o0,
    unsigned short* __restrict__ o1, unsigned short* __restrict__ o2) {
  const int bid = blockIdx.x;
  const float* in;
  unsigned short* out;
  int i;
  if (bid < 8192) {
    in = hs; out = xo; i = bid * 256 + threadIdx.x;
  } else {
    const int r = bid - 8192, z = r >> 10;
    in = (z == 0) ? w0 : (z == 1) ? w1 : w2;
    out = (z == 0) ? o0 : (z == 1) ? o1 : o2;
    i = (r & 1023) * 256 + threadIdx.x;
  }
  float4 v = ((const float4*)in)[i];
  unsigned long long rr = (unsigned long long)f2h(v.x)
                        | ((unsigned long long)f2h(v.y) << 16)
                        | ((unsigned long long)f2h(v.z) << 32)
                        | ((unsigned long long)f2h(v.w) << 48);
  ((unsigned long long*)out)[i] = rr;
}

// ---------------- fused QKV projection GEMM, BK=64, XCD-swizzled ----------------
// z==0: Qh = (X@Wq^T + bq) * (1/8*log2e)  fp16, [s][1024]   (swapped-operand path)
// z==1: Kh =  X@Wk^T + bk                 fp16, [s][1024]   (swapped-operand path)
// z==2: Vt =  X@Wv^T + bv                 fp16, transposed [bh*64+d][s]
__global__ __launch_bounds__(256) void gemm_qkv(
    const unsigned short* __restrict__ Xh,
    const unsigned short* __restrict__ Wqh, const unsigned short* __restrict__ Wkh,
    const unsigned short* __restrict__ Wvh,
    const float* __restrict__ bq, const float* __restrict__ bk, const float* __restrict__ bv,
    unsigned short* __restrict__ Qh, unsigned short* __restrict__ Kh,
    unsigned short* __restrict__ Vt) {
  __shared__ unsigned short lA[128 * 64]; // 16 KB
  __shared__ unsigned short lB[128 * 64]; // 16 KB
  const int L = blockIdx.x;
  const int xcd = L & 7, rr = L >> 3;
  const int mloc = rr & 7, widx = rr >> 3;   // widx 0..23
  const int tNi = widx & 7, z = widx >> 3;   // z 0..2
  const int tM = (xcd * 8 + mloc) * 128, tN = tNi * 128;

  const unsigned short* W = (z == 0) ? Wqh : (z == 1) ? Wkh : Wvh;
  const float* bias = (z == 0) ? bq : (z == 1) ? bk : bv;

  const int tid = threadIdx.x;
  const int wave = tid >> 6, lane = tid & 63;
  const int quad = lane >> 4, l16 = lane & 15;
  const int wr = (wave >> 1) * 64, wc = (wave & 1) * 64;

  f32x4 acc[4][4] = {};

  const int rB = tid >> 3;
  const int colOff = (((tid & 7) ^ (rB & 7))) * 8;
  const unsigned short* gA[4];
  const unsigned short* gB[4];
#pragma unroll
  for (int i = 0; i < 4; ++i) {
    gA[i] = Xh + (size_t)(tM + i * 32 + rB) * SD + colOff;
    gB[i] = W  + (size_t)(tN + i * 32 + rB) * SD + colOff;
  }
  unsigned short* dA[4];
  unsigned short* dB[4];
#pragma unroll
  for (int i = 0; i < 4; ++i) {
    dA[i] = lA + (i * 256 + wave * 64) * 8;
    dB[i] = lB + (i * 256 + wave * 64) * 8;
  }
  const int swl = l16 & 7;

  if (z == 2) {
    for (int k0 = 0; k0 < SD; k0 += 64) {
      __syncthreads();
#pragma unroll
      for (int i = 0; i < 4; ++i) gld_lds16(gA[i] + k0, dA[i]);
#pragma unroll
      for (int i = 0; i < 4; ++i) gld_lds16(gB[i] + k0, dB[i]);
      __syncthreads();
#pragma unroll
      for (int ks = 0; ks < 2; ++ks) {
        h8 af[4], bf[4];
#pragma unroll
        for (int mi = 0; mi < 4; ++mi)
          af[mi] = *(const h8*)(lA + (wr + mi * 16 + l16) * 64 + (((ks * 4 + quad) ^ swl) * 8));
#pragma unroll
        for (int ni = 0; ni < 4; ++ni)
          bf[ni] = *(const h8*)(lB + (wc + ni * 16 + l16) * 64 + (((ks * 4 + quad) ^ swl) * 8));
#pragma unroll
        for (int mi = 0; mi < 4; ++mi)
#pragma unroll
          for (int ni = 0; ni < 4; ++ni)
            acc[mi][ni] = __builtin_amdgcn_mfma_f32_16x16x32_f16(af[mi], bf[ni], acc[mi][ni], 0, 0, 0);
      }
    }
    // C/D: col=l16 -> gn, row=quad*4+r -> gm (s-direction) ; pack r -> b64
#pragma unroll
    for (int ni = 0; ni < 4; ++ni) {
      const int gn = tN + wc + ni * 16 + l16;
      const float bb = bias[gn];
#pragma unroll
      for (int mi = 0; mi < 4; ++mi) {
        const int gm = tM + wr + mi * 16 + quad * 4;
        const int vb = gm >> 11, vs = gm & 2047;
        unsigned long long wv = 0;
#pragma unroll
        for (int r = 0; r < 4; ++r)
          wv |= (unsigned long long)f2h(acc[mi][ni][r] + bb) << (16 * r);
        *(unsigned long long*)(Vt + (size_t)(vb * 1024 + gn) * SS + vs) = wv;
      }
    }
  } else {
    // swapped operands: D m-dim = W rows (gn), n-dim = X rows (gm)
    for (int k0 = 0; k0 < SD; k0 += 64) {
      __syncthreads();
#pragma unroll
      for (int i = 0; i < 4; ++i) gld_lds16(gA[i] + k0, dA[i]);
#pragma unroll
      for (int i = 0; i < 4; ++i) gld_lds16(gB[i] + k0, dB[i]);
      __syncthreads();
#pragma unroll
      for (int ks = 0; ks < 2; ++ks) {
        h8 af[4], bf[4];
#pragma unroll
        for (int mi = 0; mi < 4; ++mi)
          af[mi] = *(const h8*)(lA + (wr + mi * 16 + l16) * 64 + (((ks * 4 + quad) ^ swl) * 8));
#pragma unroll
        for (int ni = 0; ni < 4; ++ni)
          bf[ni] = *(const h8*)(lB + (wc + ni * 16 + l16) * 64 + (((ks * 4 + quad) ^ swl) * 8));
#pragma unroll
        for (int mi = 0; mi < 4; ++mi)
#pragma unroll
          for (int ni = 0; ni < 4; ++ni)
            acc[mi][ni] = __builtin_amdgcn_mfma_f32_16x16x32_f16(bf[ni], af[mi], acc[mi][ni], 0, 0, 0);
      }
    }
    // C/D: col=l16 -> gm (X row), row=quad*4+r -> gn (consecutive!) -> b64 store
    const float sc = (z == 0) ? 0.18033688011112042f : 1.0f; // 1/8*log2(e)
    unsigned short* C = (z == 0) ? Qh : Kh;
#pragma unroll
    for (int mi = 0; mi < 4; ++mi) {
      const int gm = tM + wr + mi * 16 + l16;
#pragma unroll
      for (int ni = 0; ni < 4; ++ni) {
        const int gnb = tN + wc + ni * 16 + quad * 4;
        const float4 bb4 = *(const float4*)(bias + gnb);
        unsigned long long wv;
        wv  = (unsigned long long)f2h((acc[mi][ni][0] + bb4.x) * sc);
        wv |= (unsigned long long)f2h((acc[mi][ni][1] + bb4.y) * sc) << 16;
        wv |= (unsigned long long)f2h((acc[mi][ni][2] + bb4.z) * sc) << 32;
        wv |= (unsigned long long)f2h((acc[mi][ni][3] + bb4.w) * sc) << 48;
        *(unsigned long long*)(C + (size_t)gm * SD + gnb) = wv;
      }
    }
  }
}

// ---------------- attention: 256 q/block (8 waves x 32 q), P in-register,
// 3-buffer 2-ahead pipeline with counted vmcnt + raw s_barrier (no full drain).
// Per phase kt: waitcnt vmcnt(2) [tile kt landed; tile kt+1 stays in flight]
//   -> s_barrier [all waves' tile-kt loads landed; all done reading prefetch target]
//   -> stage tile kt+2 -> compute tile kt.
// Grid 512 x 512thr = exactly 2 blocks/CU (96 KB LDS), 16 waves/CU, no tail.
__global__ __launch_bounds__(512, 4) void attn(const unsigned short* __restrict__ Qh,
                                               const unsigned short* __restrict__ Kh,
                                               const unsigned short* __restrict__ Vt,
                                               float* __restrict__ out) {
  __shared__ unsigned short lK[3][64 * 64]; // 24 KB
  __shared__ unsigned short lV[3][64 * 64]; // 24 KB
  const int tid = threadIdx.x;
  const int wave = tid >> 6, lane = tid & 63;
  const int quad = lane >> 4, l16 = lane & 15;
  // grid 512: bid = qt*64 + bh -> all 8 q-tiles of one bh share an XCD (bid%8==bh%8)
  const int bid = blockIdx.x;
  const int bh = bid & 63, qt = bid >> 6;          // qt 0..7
  const int b = bh >> 4, h = bh & 15;
  const int qs = qt * 256 + wave * 16;             // halves at +0,+128

  const unsigned short* qp0 = Qh + ((size_t)(b * SS + qs + l16)) * SD + h * 64 + quad * 8;
  h8 aq[2][2];
#pragma unroll
  for (int x = 0; x < 2; ++x) {
    aq[x][0] = *(const h8*)(qp0 + (size_t)(x * 128) * SD);
    aq[x][1] = *(const h8*)(qp0 + (size_t)(x * 128) * SD + 32);
  }

  // 512 threads cover the full 64-row tile with ONE gld_lds per array
  const int row0 = tid >> 3, cs0 = (tid & 7) ^ (row0 & 7);
  const unsigned short* kS0 = Kh + ((size_t)(b * SS + row0)) * SD + h * 64 + cs0 * 8;
  const unsigned short* vS0 = Vt + ((size_t)(bh * 64 + row0)) * SS + cs0 * 8;
  unsigned short* dK0 = &lK[0][wave * 512];
  unsigned short* dV0 = &lV[0][wave * 512];

  f32x4 ov[2][4] = {};
  float lacc[2] = {0.f, 0.f};
  const int swl = l16 & 7;
  const int ko0 = (quad ^ swl) * 8, ko1 = ((4 + quad) ^ swl) * 8;

#define STAGE(BUF) do { \
    gld_lds16(kS0, dK0 + (BUF) * 4096); \
    gld_lds16(vS0, dV0 + (BUF) * 4096); \
    kS0 += 64 * SD; vS0 += 64; \
  } while (0)

#define COMPUTE(BUF) do { \
    const unsigned short* Kt = lK[BUF]; \
    const unsigned short* Vl = lV[BUF]; \
    f32x4 s[2][4]; \
    __builtin_amdgcn_s_setprio(1); \
    _Pragma("unroll") \
    for (int nt = 0; nt < 4; ++nt) { \
      const unsigned short* kr = Kt + (nt * 16 + l16) * 64; \
      h8 kf0 = *(const h8*)(kr + ko0); \
      h8 kf1 = *(const h8*)(kr + ko1); \
      _Pragma("unroll") \
      for (int x = 0; x < 2; ++x) { \
        f32x4 z = {}; \
        z = __builtin_amdgcn_mfma_f32_16x16x32_f16(kf0, aq[x][0], z, 0, 0, 0); \
        s[x][nt] = __builtin_amdgcn_mfma_f32_16x16x32_f16(kf1, aq[x][1], z, 0, 0, 0); \
      } \
    } \
    __builtin_amdgcn_s_setprio(0); \
    h8 pb[2][2]; \
    _Pragma("unroll") \
    for (int x = 0; x < 2; ++x) { \
      unsigned ul[4], uh[4]; \
      float la = 0.f; \
      _Pragma("unroll") \
      for (int g = 0; g < 4; ++g) { \
        float p0 = __builtin_amdgcn_exp2f(s[x][g][0]); \
        float p1 = __builtin_amdgcn_exp2f(s[x][g][1]); \
        float p2 = __builtin_amdgcn_exp2f(s[x][g][2]); \
        float p3 = __builtin_amdgcn_exp2f(s[x][g][3]); \
        la += (p0 + p1) + (p2 + p3); \
        ul[g] = __builtin_bit_cast(unsigned, __builtin_amdgcn_cvt_pkrtz(p0, p1)); \
        uh[g] = __builtin_bit_cast(unsigned, __builtin_amdgcn_cvt_pkrtz(p2, p3)); \
      } \
      lacc[x] += la; \
      auto sl0 = __builtin_amdgcn_permlane32_swap(ul[0], ul[1], false, false); \
      auto tl0 = __builtin_amdgcn_permlane16_swap(sl0[0], sl0[1], false, false); \
      auto sh0 = __builtin_amdgcn_permlane32_swap(uh[0], uh[1], false, false); \
      auto th0 = __builtin_amdgcn_permlane16_swap(sh0[0], sh0[1], false, false); \
      u32x4 w0 = {tl0[0], th0[0], tl0[1], th0[1]}; \
      pb[x][0] = __builtin_bit_cast(h8, w0); \
      auto sl1 = __builtin_amdgcn_permlane32_swap(ul[2], ul[3], false, false); \
      auto tl1 = __builtin_amdgcn_permlane16_swap(sl1[0], sl1[1], false, false); \
      auto sh1 = __builtin_amdgcn_permlane32_swap(uh[2], uh[3], false, false); \
      auto th1 = __builtin_amdgcn_permlane16_swap(sh1[0], sh1[1], false, false); \
      u32x4 w1 = {tl1[0], th1[0], tl1[1], th1[1]}; \
      pb[x][1] = __builtin_bit_cast(h8, w1); \
    } \
    __builtin_amdgcn_s_setprio(1); \
    _Pragma("unroll") \
    for (int f = 0; f < 4; ++f) { \
      const unsigned short* vr = Vl + (f * 16 + l16) * 64; \
      h8 v0 = *(const h8*)(vr + ko0); \
      h8 v1 = *(const h8*)(vr + ko1); \
      _Pragma("unroll") \
      for (int x = 0; x < 2; ++x) { \
        ov[x][f] = __builtin_amdgcn_mfma_f32_16x16x32_f16(v0, pb[x][0], ov[x][f], 0, 0, 0); \
        ov[x][f] = __builtin_amdgcn_mfma_f32_16x16x32_f16(v1, pb[x][1], ov[x][f], 0, 0, 0); \
      } \
    } \
    __builtin_amdgcn_s_setprio(0); \
  } while (0)

#define PHASE(BUF, PBUF) do { \
    asm volatile("s_waitcnt vmcnt(2)" ::: "memory"); \
    __builtin_amdgcn_s_barrier(); \
    STAGE(PBUF); \
    COMPUTE(BUF); \
  } while (0)

  // prologue: tiles 0,1 -> bufs 0,1 (4 loads outstanding per wave)
  STAGE(0);
  STAGE(1);

  for (int j = 0; j < 10; ++j) {
    PHASE(0, 2);   // kt=3j  : compute buf0, prefetch -> buf2
    PHASE(1, 0);   // kt=3j+1: compute buf1, prefetch -> buf0
    PHASE(2, 1);   // kt=3j+2: compute buf2, prefetch -> buf1
  }
  // tails: kt=30 (buf0, tile31 still in flight), kt=31 (buf1)
  asm volatile("s_waitcnt vmcnt(2)" ::: "memory");
  __builtin_amdgcn_s_barrier();
  COMPUTE(0);
  asm volatile("s_waitcnt vmcnt(0)" ::: "memory");
  __builtin_amdgcn_s_barrier();
  COMPUTE(1);

#undef PHASE
#undef COMPUTE
#undef STAGE

  // epilogue: l reduce across quads (same query = l16), normalize, store
#pragma unroll
  for (int x = 0; x < 2; ++x) {
    float lt = lacc[x];
    lt += __shfl_xor(lt, 16);
    lt += __shfl_xor(lt, 32);
    const float inv = 1.0f / lt;
    float* orow = out + ((size_t)(b * SS + qs + x * 128 + l16)) * SD + h * 64 + quad * 4;
#pragma unroll
    for (int f = 0; f < 4; ++f) {
      float4 w;
      w.x = ov[x][f][0] * inv; w.y = ov[x][f][1] * inv;
      w.z = ov[x][f][2] * inv; w.w = ov[x][f][3] * inv;
      *(float4*)(orow + f * 16) = w;
    }
  }
}

extern "C" void kernel_launch(void* const* d_in, const int* in_sizes, int n_in,
                              void* d_out, int out_size, void* d_ws, size_t ws_size,
                              hipStream_t stream) {
  const float* hs = (const float*)d_in[0];
  const float* Wq = (const float*)d_in[1];
  const float* bq = (const float*)d_in[2];
  const float* Wk = (const float*)d_in[3];
  const float* bk = (const float*)d_in[4];
  const float* Wv = (const float*)d_in[5];
  const float* bv = (const float*)d_in[6];
  float* out = (float*)d_out;

  char* ws = (char*)d_ws;
  unsigned short* Xh  = (unsigned short*)(ws);
  unsigned short* Wqh = (unsigned short*)(ws + 16777216);
  unsigned short* Wkh = (unsigned short*)(ws + 16777216 + 2097152);
  unsigned short* Wvh = (unsigned short*)(ws + 16777216 + 2 * 2097152);
  unsigned short* Qh  = (unsigned short*)(ws + 16777216 + 3 * 2097152);
  unsigned short* Kh  = Qh + (size_t)SM * SD;
  unsigned short* Vt  = Kh + (size_t)SM * SD;

  cvt_all<<<dim3(8192 + 3072), dim3(256), 0, stream>>>(hs, Wq, Wk, Wv, Xh, Wqh, Wkh, Wvh);
  gemm_qkv<<<dim3(1536), dim3(256), 0, stream>>>(
      Xh, Wqh, Wkh, Wvh, bq, bk, bv, Qh, Kh, Vt);
  attn<<<dim3(SB * SH * (SS / 256)), dim3(512), 0, stream>>>(Qh, Kh, Vt, out);
}

// Round 5
// 273.940 us; speedup vs baseline: 2.0747x; 2.0747x over previous
//
#include <hip/hip_runtime.h>
#include <math.h>

// Problem constants
#define SB 4
#define SS 2048
#define SD 1024
#define SH 16
#define SHD 64
#define SM (SB * SS) // 8192 rows

using f32x4 = __attribute__((ext_vector_type(4))) float;
using h8    = __attribute__((ext_vector_type(8))) _Float16;
using h4    = __attribute__((ext_vector_type(4))) _Float16;
using fp16x2 = __fp16 __attribute__((ext_vector_type(2)));
using fp16x4 = __fp16 __attribute__((ext_vector_type(4)));
using u32x4 = __attribute__((ext_vector_type(4))) unsigned int;

__device__ __forceinline__ unsigned short f2h(float x) {
  _Float16 h = (_Float16)x;
  return __builtin_bit_cast(unsigned short, h);
}

__device__ __forceinline__ void gld_lds16(const unsigned short* g, unsigned short* l) {
  __builtin_amdgcn_global_load_lds(
      (const __attribute__((address_space(1))) unsigned int*)g,
      (__attribute__((address_space(3))) unsigned int*)l, 16, 0, 0);
}

// ---------------- fused fp32 -> fp16 convert: X (blocks 0..8191) + 3 weights ----------
__global__ __launch_bounds__(256) void cvt_all(const float* __restrict__ hs,
    const float* __restrict__ w0, const float* __restrict__ w1, const float* __restrict__ w2,
    unsigned short* __restrict__ xo, unsigned short* __restrict__ o0,
    unsigned short* __restrict__ o1, unsigned short* __restrict__ o2) {
  const int bid = blockIdx.x;
  const float* in;
  unsigned short* out;
  int i;
  if (bid < 8192) {
    in = hs; out = xo; i = bid * 256 + threadIdx.x;
  } else {
    const int r = bid - 8192, z = r >> 10;
    in = (z == 0) ? w0 : (z == 1) ? w1 : w2;
    out = (z == 0) ? o0 : (z == 1) ? o1 : o2;
    i = (r & 1023) * 256 + threadIdx.x;
  }
  float4 v = ((const float4*)in)[i];
  unsigned long long rr = (unsigned long long)f2h(v.x)
                        | ((unsigned long long)f2h(v.y) << 16)
                        | ((unsigned long long)f2h(v.z) << 32)
                        | ((unsigned long long)f2h(v.w) << 48);
  ((unsigned long long*)out)[i] = rr;
}

// ---------------- fused QKV projection GEMM, BK=64, XCD-swizzled ----------------
// z==0: Qh = (X@Wq^T + bq) * (1/8*log2e)  fp16, [s][1024]   (swapped-operand path)
// z==1: Kh =  X@Wk^T + bk                 fp16, [s][1024]   (swapped-operand path)
// z==2: Vt =  X@Wv^T + bv                 fp16, transposed [bh*64+d][s]
__global__ __launch_bounds__(256) void gemm_qkv(
    const unsigned short* __restrict__ Xh,
    const unsigned short* __restrict__ Wqh, const unsigned short* __restrict__ Wkh,
    const unsigned short* __restrict__ Wvh,
    const float* __restrict__ bq, const float* __restrict__ bk, const float* __restrict__ bv,
    unsigned short* __restrict__ Qh, unsigned short* __restrict__ Kh,
    unsigned short* __restrict__ Vt) {
  __shared__ unsigned short lA[128 * 64]; // 16 KB
  __shared__ unsigned short lB[128 * 64]; // 16 KB
  const int L = blockIdx.x;
  const int xcd = L & 7, rr = L >> 3;
  const int mloc = rr & 7, widx = rr >> 3;   // widx 0..23
  const int tNi = widx & 7, z = widx >> 3;   // z 0..2
  const int tM = (xcd * 8 + mloc) * 128, tN = tNi * 128;

  const unsigned short* W = (z == 0) ? Wqh : (z == 1) ? Wkh : Wvh;
  const float* bias = (z == 0) ? bq : (z == 1) ? bk : bv;

  const int tid = threadIdx.x;
  const int wave = tid >> 6, lane = tid & 63;
  const int quad = lane >> 4, l16 = lane & 15;
  const int wr = (wave >> 1) * 64, wc = (wave & 1) * 64;

  f32x4 acc[4][4] = {};

  const int rB = tid >> 3;
  const int colOff = (((tid & 7) ^ (rB & 7))) * 8;
  const unsigned short* gA[4];
  const unsigned short* gB[4];
#pragma unroll
  for (int i = 0; i < 4; ++i) {
    gA[i] = Xh + (size_t)(tM + i * 32 + rB) * SD + colOff;
    gB[i] = W  + (size_t)(tN + i * 32 + rB) * SD + colOff;
  }
  unsigned short* dA[4];
  unsigned short* dB[4];
#pragma unroll
  for (int i = 0; i < 4; ++i) {
    dA[i] = lA + (i * 256 + wave * 64) * 8;
    dB[i] = lB + (i * 256 + wave * 64) * 8;
  }
  const int swl = l16 & 7;

  if (z == 2) {
    for (int k0 = 0; k0 < SD; k0 += 64) {
      __syncthreads();
#pragma unroll
      for (int i = 0; i < 4; ++i) gld_lds16(gA[i] + k0, dA[i]);
#pragma unroll
      for (int i = 0; i < 4; ++i) gld_lds16(gB[i] + k0, dB[i]);
      __syncthreads();
#pragma unroll
      for (int ks = 0; ks < 2; ++ks) {
        h8 af[4], bf[4];
#pragma unroll
        for (int mi = 0; mi < 4; ++mi)
          af[mi] = *(const h8*)(lA + (wr + mi * 16 + l16) * 64 + (((ks * 4 + quad) ^ swl) * 8));
#pragma unroll
        for (int ni = 0; ni < 4; ++ni)
          bf[ni] = *(const h8*)(lB + (wc + ni * 16 + l16) * 64 + (((ks * 4 + quad) ^ swl) * 8));
#pragma unroll
        for (int mi = 0; mi < 4; ++mi)
#pragma unroll
          for (int ni = 0; ni < 4; ++ni)
            acc[mi][ni] = __builtin_amdgcn_mfma_f32_16x16x32_f16(af[mi], bf[ni], acc[mi][ni], 0, 0, 0);
      }
    }
    // C/D: col=l16 -> gn, row=quad*4+r -> gm (s-direction) ; pack r -> b64
#pragma unroll
    for (int ni = 0; ni < 4; ++ni) {
      const int gn = tN + wc + ni * 16 + l16;
      const float bb = bias[gn];
#pragma unroll
      for (int mi = 0; mi < 4; ++mi) {
        const int gm = tM + wr + mi * 16 + quad * 4;
        const int vb = gm >> 11, vs = gm & 2047;
        unsigned long long wv = 0;
#pragma unroll
        for (int r = 0; r < 4; ++r)
          wv |= (unsigned long long)f2h(acc[mi][ni][r] + bb) << (16 * r);
        *(unsigned long long*)(Vt + (size_t)(vb * 1024 + gn) * SS + vs) = wv;
      }
    }
  } else {
    // swapped operands: D m-dim = W rows (gn), n-dim = X rows (gm)
    for (int k0 = 0; k0 < SD; k0 += 64) {
      __syncthreads();
#pragma unroll
      for (int i = 0; i < 4; ++i) gld_lds16(gA[i] + k0, dA[i]);
#pragma unroll
      for (int i = 0; i < 4; ++i) gld_lds16(gB[i] + k0, dB[i]);
      __syncthreads();
#pragma unroll
      for (int ks = 0; ks < 2; ++ks) {
        h8 af[4], bf[4];
#pragma unroll
        for (int mi = 0; mi < 4; ++mi)
          af[mi] = *(const h8*)(lA + (wr + mi * 16 + l16) * 64 + (((ks * 4 + quad) ^ swl) * 8));
#pragma unroll
        for (int ni = 0; ni < 4; ++ni)
          bf[ni] = *(const h8*)(lB + (wc + ni * 16 + l16) * 64 + (((ks * 4 + quad) ^ swl) * 8));
#pragma unroll
        for (int mi = 0; mi < 4; ++mi)
#pragma unroll
          for (int ni = 0; ni < 4; ++ni)
            acc[mi][ni] = __builtin_amdgcn_mfma_f32_16x16x32_f16(bf[ni], af[mi], acc[mi][ni], 0, 0, 0);
      }
    }
    // C/D: col=l16 -> gm (X row), row=quad*4+r -> gn (consecutive!) -> b64 store
    const float sc = (z == 0) ? 0.18033688011112042f : 1.0f; // 1/8*log2(e)
    unsigned short* C = (z == 0) ? Qh : Kh;
#pragma unroll
    for (int mi = 0; mi < 4; ++mi) {
      const int gm = tM + wr + mi * 16 + l16;
#pragma unroll
      for (int ni = 0; ni < 4; ++ni) {
        const int gnb = tN + wc + ni * 16 + quad * 4;
        const float4 bb4 = *(const float4*)(bias + gnb);
        unsigned long long wv;
        wv  = (unsigned long long)f2h((acc[mi][ni][0] + bb4.x) * sc);
        wv |= (unsigned long long)f2h((acc[mi][ni][1] + bb4.y) * sc) << 16;
        wv |= (unsigned long long)f2h((acc[mi][ni][2] + bb4.z) * sc) << 32;
        wv |= (unsigned long long)f2h((acc[mi][ni][3] + bb4.w) * sc) << 48;
        *(unsigned long long*)(C + (size_t)gm * SD + gnb) = wv;
      }
    }
  }
}

// ---------------- attention: 256 q/block (8 waves x 32 q), P in-register,
// 3-buffer 2-ahead pipeline, counted vmcnt + raw s_barrier (never drains to 0
// in the main loop), ROLLING buffer offsets (wave-uniform SGPRs, small body).
// Per phase kt: waitcnt vmcnt(2) [tile kt's LDS writes landed; tile kt+1 in flight]
//   -> s_barrier [all waves see tile kt; all done reading the prefetch target]
//   -> stage tile kt+2 -> compute tile kt.
// Grid 512 x 512thr, LDS 48KB -> exactly 2 blocks/CU, 16 waves/CU.
// NOTE launch_bounds arg2 is min BLOCKS/CU on this toolchain: (512,2) -> VGPR cap 128.
// (512,4) capped VGPRs at 64 and spilled ~1.8 GB/dispatch to scratch in R4.
__global__ __launch_bounds__(512, 2) void attn(const unsigned short* __restrict__ Qh,
                                               const unsigned short* __restrict__ Kh,
                                               const unsigned short* __restrict__ Vt,
                                               float* __restrict__ out) {
  __shared__ unsigned short lK[3][64 * 64]; // 24 KB
  __shared__ unsigned short lV[3][64 * 64]; // 24 KB
  const int tid = threadIdx.x;
  const int wave = tid >> 6, lane = tid & 63;
  const int quad = lane >> 4, l16 = lane & 15;
  // grid 512: bid = qt*64 + bh -> all 8 q-tiles of one bh share an XCD (bid%8==bh%8)
  const int bid = blockIdx.x;
  const int bh = bid & 63, qt = bid >> 6;          // qt 0..7
  const int b = bh >> 4, h = bh & 15;
  const int qs = qt * 256 + wave * 16;             // halves at +0,+128

  const unsigned short* qp0 = Qh + ((size_t)(b * SS + qs + l16)) * SD + h * 64 + quad * 8;
  h8 aq[2][2];
#pragma unroll
  for (int x = 0; x < 2; ++x) {
    aq[x][0] = *(const h8*)(qp0 + (size_t)(x * 128) * SD);
    aq[x][1] = *(const h8*)(qp0 + (size_t)(x * 128) * SD + 32);
  }

  // 512 threads cover the full 64-row tile with ONE gld_lds per array
  const int row0 = tid >> 3, cs0 = (tid & 7) ^ (row0 & 7);
  const unsigned short* kS0 = Kh + ((size_t)(b * SS + row0)) * SD + h * 64 + cs0 * 8;
  const unsigned short* vS0 = Vt + ((size_t)(bh * 64 + row0)) * SS + cs0 * 8;
  unsigned short* dK0 = &lK[0][wave * 512];
  unsigned short* dV0 = &lV[0][wave * 512];
  const unsigned short* Kb = &lK[0][0];
  const unsigned short* Vb = &lV[0][0];

  f32x4 ov[2][4] = {};
  float lacc[2] = {0.f, 0.f};
  const int swl = l16 & 7;
  const int ko0 = (quad ^ swl) * 8, ko1 = ((4 + quad) ^ swl) * 8;

#define STAGE(OFF) do { \
    gld_lds16(kS0, dK0 + (OFF)); \
    gld_lds16(vS0, dV0 + (OFF)); \
    kS0 += 64 * SD; vS0 += 64; \
  } while (0)

#define COMPUTE(OFF) do { \
    const unsigned short* Kt = Kb + (OFF); \
    const unsigned short* Vl = Vb + (OFF); \
    f32x4 s[2][4]; \
    __builtin_amdgcn_s_setprio(1); \
    _Pragma("unroll") \
    for (int nt = 0; nt < 4; ++nt) { \
      const unsigned short* kr = Kt + (nt * 16 + l16) * 64; \
      h8 kf0 = *(const h8*)(kr + ko0); \
      h8 kf1 = *(const h8*)(kr + ko1); \
      _Pragma("unroll") \
      for (int x = 0; x < 2; ++x) { \
        f32x4 z = {}; \
        z = __builtin_amdgcn_mfma_f32_16x16x32_f16(kf0, aq[x][0], z, 0, 0, 0); \
        s[x][nt] = __builtin_amdgcn_mfma_f32_16x16x32_f16(kf1, aq[x][1], z, 0, 0, 0); \
      } \
    } \
    __builtin_amdgcn_s_setprio(0); \
    h8 pb[2][2]; \
    _Pragma("unroll") \
    for (int x = 0; x < 2; ++x) { \
      unsigned ul[4], uh[4]; \
      float la = 0.f; \
      _Pragma("unroll") \
      for (int g = 0; g < 4; ++g) { \
        float p0 = __builtin_amdgcn_exp2f(s[x][g][0]); \
        float p1 = __builtin_amdgcn_exp2f(s[x][g][1]); \
        float p2 = __builtin_amdgcn_exp2f(s[x][g][2]); \
        float p3 = __builtin_amdgcn_exp2f(s[x][g][3]); \
        la += (p0 + p1) + (p2 + p3); \
        ul[g] = __builtin_bit_cast(unsigned, __builtin_amdgcn_cvt_pkrtz(p0, p1)); \
        uh[g] = __builtin_bit_cast(unsigned, __builtin_amdgcn_cvt_pkrtz(p2, p3)); \
      } \
      lacc[x] += la; \
      auto sl0 = __builtin_amdgcn_permlane32_swap(ul[0], ul[1], false, false); \
      auto tl0 = __builtin_amdgcn_permlane16_swap(sl0[0], sl0[1], false, false); \
      auto sh0 = __builtin_amdgcn_permlane32_swap(uh[0], uh[1], false, false); \
      auto th0 = __builtin_amdgcn_permlane16_swap(sh0[0], sh0[1], false, false); \
      u32x4 w0 = {tl0[0], th0[0], tl0[1], th0[1]}; \
      pb[x][0] = __builtin_bit_cast(h8, w0); \
      auto sl1 = __builtin_amdgcn_permlane32_swap(ul[2], ul[3], false, false); \
      auto tl1 = __builtin_amdgcn_permlane16_swap(sl1[0], sl1[1], false, false); \
      auto sh1 = __builtin_amdgcn_permlane32_swap(uh[2], uh[3], false, false); \
      auto th1 = __builtin_amdgcn_permlane16_swap(sh1[0], sh1[1], false, false); \
      u32x4 w1 = {tl1[0], th1[0], tl1[1], th1[1]}; \
      pb[x][1] = __builtin_bit_cast(h8, w1); \
    } \
    __builtin_amdgcn_s_setprio(1); \
    _Pragma("unroll") \
    for (int f = 0; f < 4; ++f) { \
      const unsigned short* vr = Vl + (f * 16 + l16) * 64; \
      h8 v0 = *(const h8*)(vr + ko0); \
      h8 v1 = *(const h8*)(vr + ko1); \
      _Pragma("unroll") \
      for (int x = 0; x < 2; ++x) { \
        ov[x][f] = __builtin_amdgcn_mfma_f32_16x16x32_f16(v0, pb[x][0], ov[x][f], 0, 0, 0); \
        ov[x][f] = __builtin_amdgcn_mfma_f32_16x16x32_f16(v1, pb[x][1], ov[x][f], 0, 0, 0); \
      } \
    } \
    __builtin_amdgcn_s_setprio(0); \
  } while (0)

  // prologue: tiles 0,1 -> buffer offsets 0, 4096 (4 loads outstanding per wave)
  STAGE(0);
  STAGE(4096);

  int co = 0, po = 8192; // compute / prefetch buffer offsets (shorts), rotate mod 3*4096
  for (int kt = 0; kt < 30; ++kt) {
    asm volatile("s_waitcnt vmcnt(2)" ::: "memory");
    __builtin_amdgcn_s_barrier();
    STAGE(po);
    COMPUTE(co);
    co = (co == 8192) ? 0 : co + 4096;
    po = (po == 8192) ? 0 : po + 4096;
  }
  // tails: kt=30 (co=0, tile31 still in flight), kt=31 (co=4096)
  asm volatile("s_waitcnt vmcnt(2)" ::: "memory");
  __builtin_amdgcn_s_barrier();
  COMPUTE(0);
  asm volatile("s_waitcnt vmcnt(0)" ::: "memory");
  __builtin_amdgcn_s_barrier();
  COMPUTE(4096);

#undef COMPUTE
#undef STAGE

  // epilogue: l reduce across quads (same query = l16), normalize, store
#pragma unroll
  for (int x = 0; x < 2; ++x) {
    float lt = lacc[x];
    lt += __shfl_xor(lt, 16);
    lt += __shfl_xor(lt, 32);
    const float inv = 1.0f / lt;
    float* orow = out + ((size_t)(b * SS + qs + x * 128 + l16)) * SD + h * 64 + quad * 4;
#pragma unroll
    for (int f = 0; f < 4; ++f) {
      float4 w;
      w.x = ov[x][f][0] * inv; w.y = ov[x][f][1] * inv;
      w.z = ov[x][f][2] * inv; w.w = ov[x][f][3] * inv;
      *(float4*)(orow + f * 16) = w;
    }
  }
}

extern "C" void kernel_launch(void* const* d_in, const int* in_sizes, int n_in,
                              void* d_out, int out_size, void* d_ws, size_t ws_size,
                              hipStream_t stream) {
  const float* hs = (const float*)d_in[0];
  const float* Wq = (const float*)d_in[1];
  const float* bq = (const float*)d_in[2];
  const float* Wk = (const float*)d_in[3];
  const float* bk = (const float*)d_in[4];
  const float* Wv = (const float*)d_in[5];
  const float* bv = (const float*)d_in[6];
  float* out = (float*)d_out;

  char* ws = (char*)d_ws;
  unsigned short* Xh  = (unsigned short*)(ws);
  unsigned short* Wqh = (unsigned short*)(ws + 16777216);
  unsigned short* Wkh = (unsigned short*)(ws + 16777216 + 2097152);
  unsigned short* Wvh = (unsigned short*)(ws + 16777216 + 2 * 2097152);
  unsigned short* Qh  = (unsigned short*)(ws + 16777216 + 3 * 2097152);
  unsigned short* Kh  = Qh + (size_t)SM * SD;
  unsigned short* Vt  = Kh + (size_t)SM * SD;

  cvt_all<<<dim3(8192 + 3072), dim3(256), 0, stream>>>(hs, Wq, Wk, Wv, Xh, Wqh, Wkh, Wvh);
  gemm_qkv<<<dim3(1536), dim3(256), 0, stream>>>(
      Xh, Wqh, Wkh, Wvh, bq, bk, bv, Qh, Kh, Vt);
  attn<<<dim3(SB * SH * (SS / 256)), dim3(512), 0, stream>>>(Qh, Kh, Vt, out);
}

// Round 6
// 230.644 us; speedup vs baseline: 2.4642x; 1.1877x over previous
//
#include <hip/hip_runtime.h>
#include <math.h>

// Problem constants
#define SB 4
#define SS 2048
#define SD 1024
#define SH 16
#define SHD 64
#define SM (SB * SS) // 8192 rows

using f32x4 = __attribute__((ext_vector_type(4))) float;
using h8    = __attribute__((ext_vector_type(8))) _Float16;
using fp16x2 = __fp16 __attribute__((ext_vector_type(2)));
using u32x4 = __attribute__((ext_vector_type(4))) unsigned int;

__device__ __forceinline__ unsigned short f2h(float x) {
  _Float16 h = (_Float16)x;
  return __builtin_bit_cast(unsigned short, h);
}

__device__ __forceinline__ void gld_lds16(const unsigned short* g, unsigned short* l) {
  __builtin_amdgcn_global_load_lds(
      (const __attribute__((address_space(1))) unsigned int*)g,
      (__attribute__((address_space(3))) unsigned int*)l, 16, 0, 0);
}

// ---------------- fused fp32 -> fp16 convert: X (blocks 0..8191) + 3 weights ----------
__global__ __launch_bounds__(256) void cvt_all(const float* __restrict__ hs,
    const float* __restrict__ w0, const float* __restrict__ w1, const float* __restrict__ w2,
    unsigned short* __restrict__ xo, unsigned short* __restrict__ o0,
    unsigned short* __restrict__ o1, unsigned short* __restrict__ o2) {
  const int bid = blockIdx.x;
  const float* in;
  unsigned short* out;
  int i;
  if (bid < 8192) {
    in = hs; out = xo; i = bid * 256 + threadIdx.x;
  } else {
    const int r = bid - 8192, z = r >> 10;
    in = (z == 0) ? w0 : (z == 1) ? w1 : w2;
    out = (z == 0) ? o0 : (z == 1) ? o1 : o2;
    i = (r & 1023) * 256 + threadIdx.x;
  }
  float4 v = ((const float4*)in)[i];
  unsigned long long rr = (unsigned long long)f2h(v.x)
                        | ((unsigned long long)f2h(v.y) << 16)
                        | ((unsigned long long)f2h(v.z) << 32)
                        | ((unsigned long long)f2h(v.w) << 48);
  ((unsigned long long*)out)[i] = rr;
}

// ---------------- fused QKV projection GEMM, BK=64, XCD-swizzled ----------------
// z==0: Qh = (X@Wq^T + bq) * (1/8*log2e)  fp16, [s][1024]   (swapped-operand path)
// z==1: Kh =  X@Wk^T + bk                 fp16, [s][1024]   (swapped-operand path)
// z==2: Vt =  X@Wv^T + bv  fp16, transposed [bh*64+d][s], with s PERMUTED within
//        each 32-group to match attn's raw-P PV layout:
//        actual key k = k32 + a*16 + 4q + j  (a=(k>>4)&1, q=(k>>2)&3, j=k&3)
//        stored at  s' = k32 + 8q + 4a + j   (bijective within 32)
//        so attn's PV B-operand needs NO permlane redistribution.
__global__ __launch_bounds__(256) void gemm_qkv(
    const unsigned short* __restrict__ Xh,
    const unsigned short* __restrict__ Wqh, const unsigned short* __restrict__ Wkh,
    const unsigned short* __restrict__ Wvh,
    const float* __restrict__ bq, const float* __restrict__ bk, const float* __restrict__ bv,
    unsigned short* __restrict__ Qh, unsigned short* __restrict__ Kh,
    unsigned short* __restrict__ Vt) {
  __shared__ unsigned short lA[128 * 64]; // 16 KB
  __shared__ unsigned short lB[128 * 64]; // 16 KB
  const int L = blockIdx.x;
  const int xcd = L & 7, rr = L >> 3;
  const int mloc = rr & 7, widx = rr >> 3;   // widx 0..23
  const int tNi = widx & 7, z = widx >> 3;   // z 0..2
  const int tM = (xcd * 8 + mloc) * 128, tN = tNi * 128;

  const unsigned short* W = (z == 0) ? Wqh : (z == 1) ? Wkh : Wvh;
  const float* bias = (z == 0) ? bq : (z == 1) ? bk : bv;

  const int tid = threadIdx.x;
  const int wave = tid >> 6, lane = tid & 63;
  const int quad = lane >> 4, l16 = lane & 15;
  const int wr = (wave >> 1) * 64, wc = (wave & 1) * 64;

  f32x4 acc[4][4] = {};

  const int rB = tid >> 3;
  const int colOff = (((tid & 7) ^ (rB & 7))) * 8;
  const unsigned short* gA[4];
  const unsigned short* gB[4];
#pragma unroll
  for (int i = 0; i < 4; ++i) {
    gA[i] = Xh + (size_t)(tM + i * 32 + rB) * SD + colOff;
    gB[i] = W  + (size_t)(tN + i * 32 + rB) * SD + colOff;
  }
  unsigned short* dA[4];
  unsigned short* dB[4];
#pragma unroll
  for (int i = 0; i < 4; ++i) {
    dA[i] = lA + (i * 256 + wave * 64) * 8;
    dB[i] = lB + (i * 256 + wave * 64) * 8;
  }
  const int swl = l16 & 7;

  if (z == 2) {
    for (int k0 = 0; k0 < SD; k0 += 64) {
      __syncthreads();
#pragma unroll
      for (int i = 0; i < 4; ++i) gld_lds16(gA[i] + k0, dA[i]);
#pragma unroll
      for (int i = 0; i < 4; ++i) gld_lds16(gB[i] + k0, dB[i]);
      __syncthreads();
#pragma unroll
      for (int ks = 0; ks < 2; ++ks) {
        h8 af[4], bf[4];
#pragma unroll
        for (int mi = 0; mi < 4; ++mi)
          af[mi] = *(const h8*)(lA + (wr + mi * 16 + l16) * 64 + (((ks * 4 + quad) ^ swl) * 8));
#pragma unroll
        for (int ni = 0; ni < 4; ++ni)
          bf[ni] = *(const h8*)(lB + (wc + ni * 16 + l16) * 64 + (((ks * 4 + quad) ^ swl) * 8));
#pragma unroll
        for (int mi = 0; mi < 4; ++mi)
#pragma unroll
          for (int ni = 0; ni < 4; ++ni)
            acc[mi][ni] = __builtin_amdgcn_mfma_f32_16x16x32_f16(af[mi], bf[ni], acc[mi][ni], 0, 0, 0);
      }
    }
    // C/D: col=l16 -> gn, row=quad*4+r -> gm (s-direction); pack r -> b64.
    // Permuted store: gmb = tM+wr+mi*16 (s-block base); within-32 part of gmb is
    // (mi&1)*16 -> a=mi&1, q=quad, j=r. s' = (gmb&~31) + 8*quad + 4*(mi&1) + r.
#pragma unroll
    for (int ni = 0; ni < 4; ++ni) {
      const int gn = tN + wc + ni * 16 + l16;
      const float bb = bias[gn];
#pragma unroll
      for (int mi = 0; mi < 4; ++mi) {
        const int gmb = tM + wr + mi * 16;
        const int sp = (gmb & ~31) + quad * 8 + (mi & 1) * 4;  // permuted s (r adds 0..3)
        const int vb = gmb >> 11, vs = sp & 2047;
        unsigned long long wv = 0;
#pragma unroll
        for (int r = 0; r < 4; ++r)
          wv |= (unsigned long long)f2h(acc[mi][ni][r] + bb) << (16 * r);
        *(unsigned long long*)(Vt + (size_t)(vb * 1024 + gn) * SS + vs) = wv;
      }
    }
  } else {
    // swapped operands: D m-dim = W rows (gn), n-dim = X rows (gm)
    for (int k0 = 0; k0 < SD; k0 += 64) {
      __syncthreads();
#pragma unroll
      for (int i = 0; i < 4; ++i) gld_lds16(gA[i] + k0, dA[i]);
#pragma unroll
      for (int i = 0; i < 4; ++i) gld_lds16(gB[i] + k0, dB[i]);
      __syncthreads();
#pragma unroll
      for (int ks = 0; ks < 2; ++ks) {
        h8 af[4], bf[4];
#pragma unroll
        for (int mi = 0; mi < 4; ++mi)
          af[mi] = *(const h8*)(lA + (wr + mi * 16 + l16) * 64 + (((ks * 4 + quad) ^ swl) * 8));
#pragma unroll
        for (int ni = 0; ni < 4; ++ni)
          bf[ni] = *(const h8*)(lB + (wc + ni * 16 + l16) * 64 + (((ks * 4 + quad) ^ swl) * 8));
#pragma unroll
        for (int mi = 0; mi < 4; ++mi)
#pragma unroll
          for (int ni = 0; ni < 4; ++ni)
            acc[mi][ni] = __builtin_amdgcn_mfma_f32_16x16x32_f16(bf[ni], af[mi], acc[mi][ni], 0, 0, 0);
      }
    }
    // C/D: col=l16 -> gm (X row), row=quad*4+r -> gn (consecutive!) -> b64 store
    const float sc = (z == 0) ? 0.18033688011112042f : 1.0f; // 1/8*log2(e)
    unsigned short* C = (z == 0) ? Qh : Kh;
#pragma unroll
    for (int mi = 0; mi < 4; ++mi) {
      const int gm = tM + wr + mi * 16 + l16;
#pragma unroll
      for (int ni = 0; ni < 4; ++ni) {
        const int gnb = tN + wc + ni * 16 + quad * 4;
        const float4 bb4 = *(const float4*)(bias + gnb);
        unsigned long long wv;
        wv  = (unsigned long long)f2h((acc[mi][ni][0] + bb4.x) * sc);
        wv |= (unsigned long long)f2h((acc[mi][ni][1] + bb4.y) * sc) << 16;
        wv |= (unsigned long long)f2h((acc[mi][ni][2] + bb4.z) * sc) << 32;
        wv |= (unsigned long long)f2h((acc[mi][ni][3] + bb4.w) * sc) << 48;
        *(unsigned long long*)(C + (size_t)gm * SD + gnb) = wv;
      }
    }
  }
}

// ---------------- attention: 128 q/block, 32 q/wave (2 half-tiles), P in-register ----
// S^T = K·Q^T (A=K-frag K=32, B=Q-frag) -> C: col=l16=query, row=nt*16+quad*4+r=key
// RAW P path (no permlane): pb[x][0] = {ul[0],uh[0],ul[1],uh[1]} puts, at lane quad q,
// B k-slot (q,i) = key (i>>2)*16 + 4q + (i&3). Vt's s-axis is pre-permuted by gemm
// (s' = k32 + 8q + 4a + j) so the plain b128 V-frag read delivers exactly that key
// at A k-slot (q,i). The l-sum is permutation-invariant (quad reduce covers 64 keys).
// Occupancy shape: grid 1024 -> 4 blocks/CU x 4 waves = 16 waves/CU (4/SIMD).
__global__ __launch_bounds__(256, 4) void attn(const unsigned short* __restrict__ Qh,
                                               const unsigned short* __restrict__ Kh,
                                               const unsigned short* __restrict__ Vt,
                                               float* __restrict__ out) {
  __shared__ unsigned short lK[2][64 * 64]; // 16 KB
  __shared__ unsigned short lV[2][64 * 64]; // 16 KB  (32 KB total)
  const int tid = threadIdx.x;
  const int wave = tid >> 6, lane = tid & 63;
  const int quad = lane >> 4, l16 = lane & 15;
  // grid 1024: bid = qt*64 + bh -> all 16 q-tiles of one bh share an XCD (bid%8==bh%8)
  const int bid = blockIdx.x;
  const int bh = bid & 63, qt = bid >> 6;          // qt 0..15
  const int b = bh >> 4, h = bh & 15;
  const int qs = qt * 128 + wave * 16;             // halves at +0,+64

  const unsigned short* qp0 = Qh + ((size_t)(b * SS + qs + l16)) * SD + h * 64 + quad * 8;
  h8 aq[2][2];
#pragma unroll
  for (int x = 0; x < 2; ++x) {
    aq[x][0] = *(const h8*)(qp0 + (size_t)(x * 64) * SD);
    aq[x][1] = *(const h8*)(qp0 + (size_t)(x * 64) * SD + 32);
  }

  const int row0 = tid >> 3, cs0 = (tid & 7) ^ (row0 & 7);
  const int row1 = row0 + 32, cs1 = (tid & 7) ^ (row1 & 7);
  const unsigned short* kS0 = Kh + ((size_t)(b * SS + row0)) * SD + h * 64 + cs0 * 8;
  const unsigned short* kS1 = Kh + ((size_t)(b * SS + row1)) * SD + h * 64 + cs1 * 8;
  const unsigned short* vS0 = Vt + ((size_t)(bh * 64 + row0)) * SS + cs0 * 8;
  const unsigned short* vS1 = Vt + ((size_t)(bh * 64 + row1)) * SS + cs1 * 8;
  unsigned short* dK0 = &lK[0][wave * 512];
  unsigned short* dK1 = &lK[0][2048 + wave * 512];
  unsigned short* dV0 = &lV[0][wave * 512];
  unsigned short* dV1 = &lV[0][2048 + wave * 512];

  f32x4 ov[2][4] = {};
  float lacc[2] = {0.f, 0.f};
  const int swl = l16 & 7;
  const int ko0 = (quad ^ swl) * 8, ko1 = ((4 + quad) ^ swl) * 8;

  gld_lds16(kS0, dK0); gld_lds16(kS1, dK1);
  gld_lds16(vS0, dV0); gld_lds16(vS1, dV1);
  kS0 += 64 * SD; kS1 += 64 * SD; vS0 += 64; vS1 += 64;

  for (int kt = 0; kt < 32; ++kt) {
    const int buf = kt & 1;
    __syncthreads();
    if (kt < 31) {
      const int o = (buf ^ 1) * 64 * 64;
      gld_lds16(kS0, dK0 + o); gld_lds16(kS1, dK1 + o);
      gld_lds16(vS0, dV0 + o); gld_lds16(vS1, dV1 + o);
      kS0 += 64 * SD; kS1 += 64 * SD; vS0 += 64; vS1 += 64;
    }
    const unsigned short* Kt = lK[buf];
    const unsigned short* Vl = lV[buf];

    // QK^T: 16 MFMA K=32; K-frags shared by both query half-tiles
    f32x4 s[2][4]; // [half][nt]
    __builtin_amdgcn_s_setprio(1);
#pragma unroll
    for (int nt = 0; nt < 4; ++nt) {
      const unsigned short* kr = Kt + (nt * 16 + l16) * 64;
      h8 kf0 = *(const h8*)(kr + ko0);
      h8 kf1 = *(const h8*)(kr + ko1);
#pragma unroll
      for (int x = 0; x < 2; ++x) {
        f32x4 z = {};
        z = __builtin_amdgcn_mfma_f32_16x16x32_f16(kf0, aq[x][0], z, 0, 0, 0);
        s[x][nt] = __builtin_amdgcn_mfma_f32_16x16x32_f16(kf1, aq[x][1], z, 0, 0, 0);
      }
    }
    __builtin_amdgcn_s_setprio(0);

    // softmax + RAW pack (no redistribution), per half
    h8 pb[2][2];
#pragma unroll
    for (int x = 0; x < 2; ++x) {
      unsigned ul[4], uh[4];
      float la = 0.f;
#pragma unroll
      for (int g = 0; g < 4; ++g) {
        float p0 = __builtin_amdgcn_exp2f(s[x][g][0]);
        float p1 = __builtin_amdgcn_exp2f(s[x][g][1]);
        float p2 = __builtin_amdgcn_exp2f(s[x][g][2]);
        float p3 = __builtin_amdgcn_exp2f(s[x][g][3]);
        la += (p0 + p1) + (p2 + p3);
        ul[g] = __builtin_bit_cast(unsigned, __builtin_amdgcn_cvt_pkrtz(p0, p1));
        uh[g] = __builtin_bit_cast(unsigned, __builtin_amdgcn_cvt_pkrtz(p2, p3));
      }
      lacc[x] += la;
      u32x4 w0 = {ul[0], uh[0], ul[1], uh[1]};  // keys 0..31 in raw slots
      pb[x][0] = __builtin_bit_cast(h8, w0);
      u32x4 w1 = {ul[2], uh[2], ul[3], uh[3]};  // keys 32..63
      pb[x][1] = __builtin_bit_cast(h8, w1);
    }

    // PV: plain b128 V-frag reads (conflict-free); Vt pre-permuted to match raw P
    __builtin_amdgcn_s_setprio(1);
#pragma unroll
    for (int f = 0; f < 4; ++f) {
      const unsigned short* vr = Vl + (f * 16 + l16) * 64;
      h8 v0 = *(const h8*)(vr + ko0);
      h8 v1 = *(const h8*)(vr + ko1);
#pragma unroll
      for (int x = 0; x < 2; ++x) {
        ov[x][f] = __builtin_amdgcn_mfma_f32_16x16x32_f16(v0, pb[x][0], ov[x][f], 0, 0, 0);
        ov[x][f] = __builtin_amdgcn_mfma_f32_16x16x32_f16(v1, pb[x][1], ov[x][f], 0, 0, 0);
      }
    }
    __builtin_amdgcn_s_setprio(0);
  }

  // epilogue: l reduce across quads (same query = l16), normalize, store
#pragma unroll
  for (int x = 0; x < 2; ++x) {
    float lt = lacc[x];
    lt += __shfl_xor(lt, 16);
    lt += __shfl_xor(lt, 32);
    const float inv = 1.0f / lt;
    float* orow = out + ((size_t)(b * SS + qs + x * 64 + l16)) * SD + h * 64 + quad * 4;
#pragma unroll
    for (int f = 0; f < 4; ++f) {
      float4 w;
      w.x = ov[x][f][0] * inv; w.y = ov[x][f][1] * inv;
      w.z = ov[x][f][2] * inv; w.w = ov[x][f][3] * inv;
      *(float4*)(orow + f * 16) = w;
    }
  }
}

extern "C" void kernel_launch(void* const* d_in, const int* in_sizes, int n_in,
                              void* d_out, int out_size, void* d_ws, size_t ws_size,
                              hipStream_t stream) {
  const float* hs = (const float*)d_in[0];
  const float* Wq = (const float*)d_in[1];
  const float* bq = (const float*)d_in[2];
  const float* Wk = (const float*)d_in[3];
  const float* bk = (const float*)d_in[4];
  const float* Wv = (const float*)d_in[5];
  const float* bv = (const float*)d_in[6];
  float* out = (float*)d_out;

  char* ws = (char*)d_ws;
  unsigned short* Xh  = (unsigned short*)(ws);
  unsigned short* Wqh = (unsigned short*)(ws + 16777216);
  unsigned short* Wkh = (unsigned short*)(ws + 16777216 + 2097152);
  unsigned short* Wvh = (unsigned short*)(ws + 16777216 + 2 * 2097152);
  unsigned short* Qh  = (unsigned short*)(ws + 16777216 + 3 * 2097152);
  unsigned short* Kh  = Qh + (size_t)SM * SD;
  unsigned short* Vt  = Kh + (size_t)SM * SD;

  cvt_all<<<dim3(8192 + 3072), dim3(256), 0, stream>>>(hs, Wq, Wk, Wv, Xh, Wqh, Wkh, Wvh);
  gemm_qkv<<<dim3(1536), dim3(256), 0, stream>>>(
      Xh, Wqh, Wkh, Wvh, bq, bk, bv, Qh, Kh, Vt);
  attn<<<dim3(SB * SH * (SS / 128)), dim3(256), 0, stream>>>(Qh, Kh, Vt, out);
}